// Round 9
// baseline (523.731 us; speedup 1.0000x reference)
//
#include <hip/hip_runtime.h>
#include <hip/hip_bf16.h>
#include <math.h>

// BahdanauAttention, round 8 (resubmit): occupancy fix for k_scores — wave tile
// 32x128 (acc 64 AGPR), BM=64, 4 waves/SIMD via __launch_bounds__(256,4).
// B=64, S=2048, E=512, D=512, A=256.
//
// ws layout (bytes):
//   [0,      64K)   dec_feat (B*A fp32)
//   [64K,   576K)   scores   (B*S fp32)  -- reused as ctx partials after softmax
//   [576K,  832K)   Bhi pack (A*E bf16, fragment-linear)
//   [832K, 1088K)   Blo pack (A*E bf16, fragment-linear)

#define B_ 64
#define S_ 2048
#define E_ 512
#define D_ 512
#define A_ 256

typedef __attribute__((ext_vector_type(8))) short bf16x8;
typedef __attribute__((ext_vector_type(16))) float f32x16;

__device__ __forceinline__ unsigned fbits(float x) { union { float f; unsigned u; } a; a.f = x; return a.u; }
__device__ __forceinline__ float bitsf(unsigned u) { union { unsigned u; float f; } a; a.u = u; return a.f; }

__device__ __forceinline__ short bf16_rne(float x) {
    unsigned u = fbits(x);
    unsigned r = u + 0x7FFFu + ((u >> 16) & 1u);
    return (short)(r >> 16);
}

__device__ __forceinline__ float fast_tanh(float x) {
    // tanh(x) = 1 - 2/(exp(2x)+1); rcp(22-bit) fine vs fp32 tolerance
    float e = __expf(2.f * x);
    return 1.f - 2.f * __builtin_amdgcn_rcpf(e + 1.f);
}

// Split 8 fp32 -> bf16 hi (trunc) + bf16 lo (trunc of exact remainder).
// Error: |x - hi - lo| <= 2^-17 |x|. 6 VALU per elem pair via v_perm_b32.
__device__ __forceinline__ void split_row(const float4& xa, const float4& xb,
                                          bf16x8& hi, bf16x8& lo) {
    float xs[8] = {xa.x, xa.y, xa.z, xa.w, xb.x, xb.y, xb.z, xb.w};
    union { bf16x8 v; unsigned u[4]; } H, L;
#pragma unroll
    for (int p = 0; p < 4; ++p) {
        unsigned u0 = fbits(xs[2 * p]), u1 = fbits(xs[2 * p + 1]);
        unsigned h0 = u0 & 0xFFFF0000u, h1 = u1 & 0xFFFF0000u;
        H.u[p] = __builtin_amdgcn_perm(u1, u0, 0x07060302u);  // [hi16(x1):hi16(x0)]
        float r0 = xs[2 * p] - bitsf(h0), r1 = xs[2 * p + 1] - bitsf(h1);
        L.u[p] = __builtin_amdgcn_perm(fbits(r1), fbits(r0), 0x07060302u);
    }
    hi = H.v;
    lo = L.v;
}

// ---------------------------------------------------------------------------
// K0: W_enc (A,E) fp32 -> Bhi/Blo bf16 in fragment-linear packed layout.
// Element (c,k) -> x8-unit index ((kb*8 + cg)*2 + half)*32 + cin, elem j
//   kb=k>>4, half=(k>>3)&1, j=k&7, cg=c>>5, cin=c&31.
__global__ __launch_bounds__(256) void k_wprep(const float* __restrict__ We,
                                               unsigned short* __restrict__ bhi,
                                               unsigned short* __restrict__ blo) {
    int idx = (blockIdx.x * 256 + threadIdx.x) * 4;  // 128 blocks; idx = c*512 + k
    int c = idx >> 9, k = idx & 511;
    int kb = k >> 4, half = (k >> 3) & 1, j = k & 7;
    int cg = c >> 5, cin = c & 31;
    int p = (((kb * 8 + cg) * 2 + half) * 32 + cin) * 8 + j;  // 4 consecutive j's
    float4 w = *(const float4*)&We[idx];
    float xs[4] = {w.x, w.y, w.z, w.w};
    unsigned short hh[4], ll[4];
#pragma unroll
    for (int i = 0; i < 4; ++i) {
        unsigned u = fbits(xs[i]);
        unsigned r = u + 0x7FFFu + ((u >> 16) & 1u);  // RNE hi
        hh[i] = (unsigned short)(r >> 16);
        ll[i] = (unsigned short)bf16_rne(xs[i] - bitsf(r & 0xFFFF0000u));
    }
    ushort4 hv = {hh[0], hh[1], hh[2], hh[3]};
    ushort4 lv = {ll[0], ll[1], ll[2], ll[3]};
    *(ushort4*)&bhi[p] = hv;
    *(ushort4*)&blo[p] = lv;
}

// ---------------------------------------------------------------------------
// K1: dec_feat[b][a] = sum_d dec[b][d] * W_dec[a][d]   (256 blocks)
__global__ __launch_bounds__(256) void k_decfeat(const float* __restrict__ dec,
                                                 const float* __restrict__ Wd,
                                                 float* __restrict__ out) {
    __shared__ float h[D_];
    __shared__ float red[4][64];
    const int b = blockIdx.x >> 2, a0 = (blockIdx.x & 3) * 64;
    const int t = threadIdx.x;
    for (int i = t; i < D_; i += 256) h[i] = dec[b * D_ + i];
    __syncthreads();
    const int a = a0 + (t & 63), part = t >> 6;
    const float4* w4 = (const float4*)(Wd + (size_t)a * D_ + part * 128);
    const float* hp = h + part * 128;
    float acc = 0.f;
#pragma unroll 8
    for (int d4 = 0; d4 < 32; ++d4) {
        float4 w = w4[d4];
        acc += w.x * hp[d4 * 4 + 0] + w.y * hp[d4 * 4 + 1] +
               w.z * hp[d4 * 4 + 2] + w.w * hp[d4 * 4 + 3];
    }
    red[part][t & 63] = acc;
    __syncthreads();
    if (t < 64)
        out[b * A_ + a0 + t] = red[0][t] + red[1][t] + red[2][t] + red[3][t];
}

// ---------------------------------------------------------------------------
// K2: scores = v . tanh(X @ W^T + decf), 3-pass split-bf16 MFMA 32x32x16.
// 256 thr = 4 waves; wave (rh=w>>1, ch=w&1) owns rows rh*32..+31 x cols
// ch*128..+127. Block = 64 rows x 256 cols (full A reduced in-block).
// acc = 64 AGPR/thread; __launch_bounds__(256,4) caps 128 regs -> 4 waves/SIMD.
// rh-paired waves load identical B frags -> L1 hits. No LDS staging, no
// K-loop barriers.
__global__ __launch_bounds__(256, 4) void k_scores(
    const float* __restrict__ X,                // (B*S, E)
    const unsigned short* __restrict__ bhi,     // packed
    const unsigned short* __restrict__ blo,     // packed
    const float* __restrict__ decf,             // (B, A)
    const float* __restrict__ v,                // (A)
    float* __restrict__ scores) {               // (B*S)
    __shared__ float partial[2][2][32];         // [rh][ch][row]

    const int t = threadIdx.x;
    const int w = t >> 6, l = t & 63;
    const int rh = w >> 1, ch = w & 1;
    const int m0 = blockIdx.x * 64;
    const int row0 = m0 + rh * 32 + (l & 31);

    const float* xp = X + (size_t)row0 * E_ + ((l >> 5) * 8);
    const bf16x8* bhv = ((const bf16x8*)bhi) + ch * 256 + l;
    const bf16x8* blv = ((const bf16x8*)blo) + ch * 256 + l;

    f32x16 acc[4];
#pragma unroll
    for (int tt = 0; tt < 4; ++tt)
#pragma unroll
        for (int i = 0; i < 16; ++i) acc[tt][i] = 0.f;

    for (int kb = 0; kb < 32; ++kb) {
        // X load + split (VALU work hides the B L2 latency below)
        float4 xa = *(const float4*)(xp + kb * 16);
        float4 xb = *(const float4*)(xp + kb * 16 + 4);
        bf16x8 ah, al;
        split_row(xa, xb, ah, al);

        // batch 0: col-tiles 0,1
        {
            bf16x8 f0h = bhv[(kb * 8 + 0) * 64];
            bf16x8 f1h = bhv[(kb * 8 + 1) * 64];
            bf16x8 f0l = blv[(kb * 8 + 0) * 64];
            bf16x8 f1l = blv[(kb * 8 + 1) * 64];
            acc[0] = __builtin_amdgcn_mfma_f32_32x32x16_bf16(ah, f0h, acc[0], 0, 0, 0);
            acc[1] = __builtin_amdgcn_mfma_f32_32x32x16_bf16(ah, f1h, acc[1], 0, 0, 0);
            acc[0] = __builtin_amdgcn_mfma_f32_32x32x16_bf16(al, f0h, acc[0], 0, 0, 0);
            acc[1] = __builtin_amdgcn_mfma_f32_32x32x16_bf16(al, f1h, acc[1], 0, 0, 0);
            acc[0] = __builtin_amdgcn_mfma_f32_32x32x16_bf16(ah, f0l, acc[0], 0, 0, 0);
            acc[1] = __builtin_amdgcn_mfma_f32_32x32x16_bf16(ah, f1l, acc[1], 0, 0, 0);
        }
        // batch 1: col-tiles 2,3
        {
            bf16x8 f2h = bhv[(kb * 8 + 2) * 64];
            bf16x8 f3h = bhv[(kb * 8 + 3) * 64];
            bf16x8 f2l = blv[(kb * 8 + 2) * 64];
            bf16x8 f3l = blv[(kb * 8 + 3) * 64];
            acc[2] = __builtin_amdgcn_mfma_f32_32x32x16_bf16(ah, f2h, acc[2], 0, 0, 0);
            acc[3] = __builtin_amdgcn_mfma_f32_32x32x16_bf16(ah, f3h, acc[3], 0, 0, 0);
            acc[2] = __builtin_amdgcn_mfma_f32_32x32x16_bf16(al, f2h, acc[2], 0, 0, 0);
            acc[3] = __builtin_amdgcn_mfma_f32_32x32x16_bf16(al, f3h, acc[3], 0, 0, 0);
            acc[2] = __builtin_amdgcn_mfma_f32_32x32x16_bf16(ah, f2l, acc[2], 0, 0, 0);
            acc[3] = __builtin_amdgcn_mfma_f32_32x32x16_bf16(ah, f3l, acc[3], 0, 0, 0);
        }
    }

    // epilogue: + decf, tanh, * v, reduce over A (cols), then rows via LDS
    const int b = m0 >> 11;  // m0 / S_
    const float* df = decf + b * A_;
    float sums[16];
#pragma unroll
    for (int r = 0; r < 16; ++r) sums[r] = 0.f;
#pragma unroll
    for (int tt = 0; tt < 4; ++tt) {
        int a = ch * 128 + tt * 32 + (l & 31);
        float vv = v[a], dd = df[a];
#pragma unroll
        for (int r = 0; r < 16; ++r)
            sums[r] += vv * fast_tanh(acc[tt][r] + dd);
    }
#pragma unroll
    for (int r = 0; r < 16; ++r) {
        sums[r] += __shfl_xor(sums[r], 1);
        sums[r] += __shfl_xor(sums[r], 2);
        sums[r] += __shfl_xor(sums[r], 4);
        sums[r] += __shfl_xor(sums[r], 8);
        sums[r] += __shfl_xor(sums[r], 16);
    }
    if ((l & 31) == 0) {
#pragma unroll
        for (int r = 0; r < 16; ++r) {
            int rit = (r & 3) + 8 * (r >> 2) + 4 * (l >> 5);  // C/D row map (m74/m101)
            partial[rh][ch][rit] = sums[r];
        }
    }
    __syncthreads();
    if (t < 64)
        scores[m0 + t] = partial[t >> 5][0][t & 31] + partial[t >> 5][1][t & 31];
}

// ---------------------------------------------------------------------------
// K3: masked softmax over S per batch row
__global__ __launch_bounds__(256) void k_softmax(const float* __restrict__ scores,
                                                 const int* __restrict__ mask,
                                                 float* __restrict__ weights) {
    const int b = blockIdx.x, t = threadIdx.x;
    const int wave = t >> 6, lane = t & 63;
    __shared__ float red[4];

    float sc[8];
    float mx = -INFINITY;
#pragma unroll
    for (int i = 0; i < 8; ++i) {
        int s = t + i * 256;
        float x = scores[b * S_ + s];
        if (mask[b * S_ + s] == 0) x = -INFINITY;
        sc[i] = x;
        mx = fmaxf(mx, x);
    }
#pragma unroll
    for (int off = 32; off >= 1; off >>= 1) mx = fmaxf(mx, __shfl_xor(mx, off));
    if (lane == 0) red[wave] = mx;
    __syncthreads();
    mx = fmaxf(fmaxf(red[0], red[1]), fmaxf(red[2], red[3]));

    float sum = 0.f;
#pragma unroll
    for (int i = 0; i < 8; ++i) {
        float e = expf(sc[i] - mx);
        sc[i] = e;
        sum += e;
    }
#pragma unroll
    for (int off = 32; off >= 1; off >>= 1) sum += __shfl_xor(sum, off);
    __syncthreads();
    if (lane == 0) red[wave] = sum;
    __syncthreads();
    float total = red[0] + red[1] + red[2] + red[3];
    float inv = 1.f / total;
#pragma unroll
    for (int i = 0; i < 8; ++i) {
        int s = t + i * 256;
        weights[b * S_ + s] = sc[i] * inv;
    }
}

// ---------------------------------------------------------------------------
// K4a: partial context over S-segments. 2048 blocks (b, e-chunk, seg).
__global__ __launch_bounds__(256) void k_ctx_part(const float* __restrict__ X,
                                                  const float* __restrict__ weights,
                                                  float* __restrict__ part) {
    const int bid = blockIdx.x;
    const int b = bid >> 5, chunk = (bid & 31) >> 2, seg = bid & 3;
    const int t = threadIdx.x;
    __shared__ float wl[512];
    __shared__ float red[16][64];

    const int s0 = seg * 512;
    for (int i = t; i < 512; i += 256) wl[i] = weights[b * S_ + s0 + i];
    __syncthreads();

    const int lane16 = t & 15, sg = t >> 4;
    const int e0 = chunk * 64 + lane16 * 4;
    float4 acc = {0.f, 0.f, 0.f, 0.f};
#pragma unroll 4
    for (int s = sg; s < 512; s += 16) {
        float wgt = wl[s];
        float4 x = *(const float4*)&X[((size_t)b * S_ + s0 + s) * E_ + e0];
        acc.x = fmaf(wgt, x.x, acc.x);
        acc.y = fmaf(wgt, x.y, acc.y);
        acc.z = fmaf(wgt, x.z, acc.z);
        acc.w = fmaf(wgt, x.w, acc.w);
    }
    red[sg][lane16 * 4 + 0] = acc.x;
    red[sg][lane16 * 4 + 1] = acc.y;
    red[sg][lane16 * 4 + 2] = acc.z;
    red[sg][lane16 * 4 + 3] = acc.w;
    __syncthreads();
    if (t < 64) {
        float s = 0.f;
#pragma unroll
        for (int g = 0; g < 16; ++g) s += red[g][t];
        part[((size_t)b * 4 + seg) * E_ + chunk * 64 + t] = s;
    }
}

// K4b: reduce the 4 segments. 64 blocks x 512 threads.
__global__ __launch_bounds__(512) void k_ctx_final(const float* __restrict__ part,
                                                   float* __restrict__ ctx) {
    const int b = blockIdx.x, e = threadIdx.x;
    const float* p = part + (size_t)b * 4 * E_ + e;
    ctx[b * E_ + e] = p[0] + p[E_] + p[2 * E_] + p[3 * E_];
}

// ---------------------------------------------------------------------------
extern "C" void kernel_launch(void* const* d_in, const int* in_sizes, int n_in,
                              void* d_out, int out_size, void* d_ws, size_t ws_size,
                              hipStream_t stream) {
    const float* enc  = (const float*)d_in[0];
    const float* dec  = (const float*)d_in[1];
    const int*   mask = (const int*)d_in[2];
    const float* We   = (const float*)d_in[3];
    const float* Wd   = (const float*)d_in[4];
    const float* v    = (const float*)d_in[5];

    float* out     = (float*)d_out;
    float* ctx     = out;             // (B,E)
    float* weights = out + B_ * E_;   // (B,S)

    char* ws = (char*)d_ws;
    float*          ws_dec    = (float*)(ws);
    float*          ws_scores = (float*)(ws + (64 << 10));
    unsigned short* ws_bhi    = (unsigned short*)(ws + (576 << 10));
    unsigned short* ws_blo    = (unsigned short*)(ws + (832 << 10));
    float*          ws_part   = ws_scores;  // reuse after softmax consumed scores

    k_wprep<<<128, 256, 0, stream>>>(We, ws_bhi, ws_blo);
    k_decfeat<<<256, 256, 0, stream>>>(dec, Wd, ws_dec);
    k_scores<<<(B_ * S_) / 64, 256, 0, stream>>>(enc, ws_bhi, ws_blo, ws_dec, v, ws_scores);
    k_softmax<<<B_, 256, 0, stream>>>(ws_scores, mask, weights);
    k_ctx_part<<<B_ * 32, 256, 0, stream>>>(enc, weights, ws_part);
    k_ctx_final<<<B_, 512, 0, stream>>>(ws_part, ctx);
}

// Round 10
// 475.363 us; speedup vs baseline: 1.1017x; 1.1017x over previous
//
#include <hip/hip_runtime.h>
#include <hip/hip_bf16.h>
#include <math.h>

// BahdanauAttention, round 10: revert to BM=128 (round-7 structure, best
// measured) + X register prefetch depth-1 to hide HBM/L3 latency on the
// critical path. B=64, S=2048, E=512, D=512, A=256.
//
// ws layout (bytes):
//   [0,      64K)   dec_feat (B*A fp32)
//   [64K,   576K)   scores   (B*S fp32)  -- reused as ctx partials after softmax
//   [576K,  832K)   Bhi pack (A*E bf16, fragment-linear)
//   [832K, 1088K)   Blo pack (A*E bf16, fragment-linear)

#define B_ 64
#define S_ 2048
#define E_ 512
#define D_ 512
#define A_ 256

typedef __attribute__((ext_vector_type(8))) short bf16x8;
typedef __attribute__((ext_vector_type(16))) float f32x16;

__device__ __forceinline__ unsigned fbits(float x) { union { float f; unsigned u; } a; a.f = x; return a.u; }
__device__ __forceinline__ float bitsf(unsigned u) { union { unsigned u; float f; } a; a.u = u; return a.f; }

__device__ __forceinline__ short bf16_rne(float x) {
    unsigned u = fbits(x);
    unsigned r = u + 0x7FFFu + ((u >> 16) & 1u);
    return (short)(r >> 16);
}

__device__ __forceinline__ float fast_tanh(float x) {
    // tanh(x) = 1 - 2/(exp(2x)+1); rcp(22-bit) fine vs fp32 tolerance
    float e = __expf(2.f * x);
    return 1.f - 2.f * __builtin_amdgcn_rcpf(e + 1.f);
}

// Split 8 fp32 -> bf16 hi (trunc) + bf16 lo (trunc of exact remainder).
// Error: |x - hi - lo| <= 2^-17 |x|. 6 VALU per elem pair via v_perm_b32.
__device__ __forceinline__ void split_row(const float4& xa, const float4& xb,
                                          bf16x8& hi, bf16x8& lo) {
    float xs[8] = {xa.x, xa.y, xa.z, xa.w, xb.x, xb.y, xb.z, xb.w};
    union { bf16x8 v; unsigned u[4]; } H, L;
#pragma unroll
    for (int p = 0; p < 4; ++p) {
        unsigned u0 = fbits(xs[2 * p]), u1 = fbits(xs[2 * p + 1]);
        unsigned h0 = u0 & 0xFFFF0000u, h1 = u1 & 0xFFFF0000u;
        H.u[p] = __builtin_amdgcn_perm(u1, u0, 0x07060302u);  // [hi16(x1):hi16(x0)]
        float r0 = xs[2 * p] - bitsf(h0), r1 = xs[2 * p + 1] - bitsf(h1);
        L.u[p] = __builtin_amdgcn_perm(fbits(r1), fbits(r0), 0x07060302u);
    }
    hi = H.v;
    lo = L.v;
}

// ---------------------------------------------------------------------------
// K0: W_enc (A,E) fp32 -> Bhi/Blo bf16 in fragment-linear packed layout.
// Element (c,k) -> x8-unit index ((kb*8 + cg)*2 + half)*32 + cin, elem j
//   kb=k>>4, half=(k>>3)&1, j=k&7, cg=c>>5, cin=c&31.
__global__ __launch_bounds__(256) void k_wprep(const float* __restrict__ We,
                                               unsigned short* __restrict__ bhi,
                                               unsigned short* __restrict__ blo) {
    int idx = (blockIdx.x * 256 + threadIdx.x) * 4;  // 128 blocks; idx = c*512 + k
    int c = idx >> 9, k = idx & 511;
    int kb = k >> 4, half = (k >> 3) & 1, j = k & 7;
    int cg = c >> 5, cin = c & 31;
    int p = (((kb * 8 + cg) * 2 + half) * 32 + cin) * 8 + j;  // 4 consecutive j's
    float4 w = *(const float4*)&We[idx];
    float xs[4] = {w.x, w.y, w.z, w.w};
    unsigned short hh[4], ll[4];
#pragma unroll
    for (int i = 0; i < 4; ++i) {
        unsigned u = fbits(xs[i]);
        unsigned r = u + 0x7FFFu + ((u >> 16) & 1u);  // RNE hi
        hh[i] = (unsigned short)(r >> 16);
        ll[i] = (unsigned short)bf16_rne(xs[i] - bitsf(r & 0xFFFF0000u));
    }
    ushort4 hv = {hh[0], hh[1], hh[2], hh[3]};
    ushort4 lv = {ll[0], ll[1], ll[2], ll[3]};
    *(ushort4*)&bhi[p] = hv;
    *(ushort4*)&blo[p] = lv;
}

// ---------------------------------------------------------------------------
// K1: dec_feat[b][a] = sum_d dec[b][d] * W_dec[a][d]   (256 blocks)
__global__ __launch_bounds__(256) void k_decfeat(const float* __restrict__ dec,
                                                 const float* __restrict__ Wd,
                                                 float* __restrict__ out) {
    __shared__ float h[D_];
    __shared__ float red[4][64];
    const int b = blockIdx.x >> 2, a0 = (blockIdx.x & 3) * 64;
    const int t = threadIdx.x;
    for (int i = t; i < D_; i += 256) h[i] = dec[b * D_ + i];
    __syncthreads();
    const int a = a0 + (t & 63), part = t >> 6;
    const float4* w4 = (const float4*)(Wd + (size_t)a * D_ + part * 128);
    const float* hp = h + part * 128;
    float acc = 0.f;
#pragma unroll 8
    for (int d4 = 0; d4 < 32; ++d4) {
        float4 w = w4[d4];
        acc += w.x * hp[d4 * 4 + 0] + w.y * hp[d4 * 4 + 1] +
               w.z * hp[d4 * 4 + 2] + w.w * hp[d4 * 4 + 3];
    }
    red[part][t & 63] = acc;
    __syncthreads();
    if (t < 64)
        out[b * A_ + a0 + t] = red[0][t] + red[1][t] + red[2][t] + red[3][t];
}

// ---------------------------------------------------------------------------
// K2: scores = v . tanh(X @ W^T + decf), 3-pass split-bf16 MFMA 32x32x16.
// 256 thr = 4 waves; wave (rh=w>>1, ch=w&1) owns rows rh*64..+63 (two 32-row
// tiles sharing B frags) x cols ch*128..+127. Block = 128 rows x 256 cols.
// X prefetch depth-1: kb+1's loads issue before kb's MFMAs, hiding ~900cyc
// HBM/L3 latency under the ~1000cyc iteration. 2 waves/SIMD, ~240 regs.
__global__ __launch_bounds__(256, 2) void k_scores(
    const float* __restrict__ X,                // (B*S, E)
    const unsigned short* __restrict__ bhi,     // packed
    const unsigned short* __restrict__ blo,     // packed
    const float* __restrict__ decf,             // (B, A)
    const float* __restrict__ v,                // (A)
    float* __restrict__ scores) {               // (B*S)
    __shared__ float partial[2][2][2][32];      // [rh][tile][ch][row]

    const int t = threadIdx.x;
    const int w = t >> 6, l = t & 63;
    const int rh = w >> 1, ch = w & 1;
    const int m0 = blockIdx.x * 128;
    const int ka = (l >> 5) * 8;                // k-offset of this half-wave
    const int row0 = m0 + rh * 64 + (l & 31);

    const float* xp0 = X + (size_t)row0 * E_ + ka;
    const float* xp1 = xp0 + 32 * E_;
    const bf16x8* bhv = ((const bf16x8*)bhi) + ch * 256 + l;
    const bf16x8* blv = ((const bf16x8*)blo) + ch * 256 + l;

    f32x16 acc0[4], acc1[4];
#pragma unroll
    for (int tt = 0; tt < 4; ++tt)
#pragma unroll
        for (int i = 0; i < 16; ++i) { acc0[tt][i] = 0.f; acc1[tt][i] = 0.f; }

    // prefetch X for kb=0
    float4 xa0 = *(const float4*)(xp0);
    float4 xb0 = *(const float4*)(xp0 + 4);
    float4 xa1 = *(const float4*)(xp1);
    float4 xb1 = *(const float4*)(xp1 + 4);

    for (int kb = 0; kb < 32; ++kb) {
        // consume prefetched X
        float4 ca0 = xa0, cb0 = xb0, ca1 = xa1, cb1 = xb1;
        // issue next-iteration X loads NOW (latency hides under this iter)
        if (kb < 31) {
            xa0 = *(const float4*)(xp0 + (kb + 1) * 16);
            xb0 = *(const float4*)(xp0 + (kb + 1) * 16 + 4);
            xa1 = *(const float4*)(xp1 + (kb + 1) * 16);
            xb1 = *(const float4*)(xp1 + (kb + 1) * 16 + 4);
        }
        // B frags (L2-resident; rh-paired waves hit L1 on identical addrs)
        bf16x8 fh[4], fl[4];
#pragma unroll
        for (int tt = 0; tt < 4; ++tt) fh[tt] = bhv[(kb * 8 + tt) * 64];
#pragma unroll
        for (int tt = 0; tt < 4; ++tt) fl[tt] = blv[(kb * 8 + tt) * 64];

        bf16x8 ah0, al0, ah1, al1;
        split_row(ca0, cb0, ah0, al0);
        split_row(ca1, cb1, ah1, al1);

#pragma unroll
        for (int tt = 0; tt < 4; ++tt)
            acc0[tt] = __builtin_amdgcn_mfma_f32_32x32x16_bf16(ah0, fh[tt], acc0[tt], 0, 0, 0);
#pragma unroll
        for (int tt = 0; tt < 4; ++tt)
            acc1[tt] = __builtin_amdgcn_mfma_f32_32x32x16_bf16(ah1, fh[tt], acc1[tt], 0, 0, 0);
#pragma unroll
        for (int tt = 0; tt < 4; ++tt)
            acc0[tt] = __builtin_amdgcn_mfma_f32_32x32x16_bf16(al0, fh[tt], acc0[tt], 0, 0, 0);
#pragma unroll
        for (int tt = 0; tt < 4; ++tt)
            acc1[tt] = __builtin_amdgcn_mfma_f32_32x32x16_bf16(al1, fh[tt], acc1[tt], 0, 0, 0);
#pragma unroll
        for (int tt = 0; tt < 4; ++tt)
            acc0[tt] = __builtin_amdgcn_mfma_f32_32x32x16_bf16(ah0, fl[tt], acc0[tt], 0, 0, 0);
#pragma unroll
        for (int tt = 0; tt < 4; ++tt)
            acc1[tt] = __builtin_amdgcn_mfma_f32_32x32x16_bf16(ah1, fl[tt], acc1[tt], 0, 0, 0);
    }

    // epilogue: + decf, tanh, * v, reduce over A (cols), then rows via LDS
    const int b = m0 >> 11;  // m0 / S_
    const float* df = decf + b * A_;
    float s0[16], s1[16];
#pragma unroll
    for (int r = 0; r < 16; ++r) { s0[r] = 0.f; s1[r] = 0.f; }
#pragma unroll
    for (int tt = 0; tt < 4; ++tt) {
        int a = ch * 128 + tt * 32 + (l & 31);
        float vv = v[a], dd = df[a];
#pragma unroll
        for (int r = 0; r < 16; ++r) {
            s0[r] += vv * fast_tanh(acc0[tt][r] + dd);
            s1[r] += vv * fast_tanh(acc1[tt][r] + dd);
        }
    }
#pragma unroll
    for (int r = 0; r < 16; ++r) {
        s0[r] += __shfl_xor(s0[r], 1);
        s0[r] += __shfl_xor(s0[r], 2);
        s0[r] += __shfl_xor(s0[r], 4);
        s0[r] += __shfl_xor(s0[r], 8);
        s0[r] += __shfl_xor(s0[r], 16);
        s1[r] += __shfl_xor(s1[r], 1);
        s1[r] += __shfl_xor(s1[r], 2);
        s1[r] += __shfl_xor(s1[r], 4);
        s1[r] += __shfl_xor(s1[r], 8);
        s1[r] += __shfl_xor(s1[r], 16);
    }
    if ((l & 31) == 0) {
#pragma unroll
        for (int r = 0; r < 16; ++r) {
            int rit = (r & 3) + 8 * (r >> 2) + 4 * (l >> 5);  // C/D row map (m74/m101)
            partial[rh][0][ch][rit] = s0[r];
            partial[rh][1][ch][rit] = s1[r];
        }
    }
    __syncthreads();
    if (t < 128)
        scores[m0 + t] = partial[t >> 6][(t >> 5) & 1][0][t & 31] +
                         partial[t >> 6][(t >> 5) & 1][1][t & 31];
}

// ---------------------------------------------------------------------------
// K3: masked softmax over S per batch row
__global__ __launch_bounds__(256) void k_softmax(const float* __restrict__ scores,
                                                 const int* __restrict__ mask,
                                                 float* __restrict__ weights) {
    const int b = blockIdx.x, t = threadIdx.x;
    const int wave = t >> 6, lane = t & 63;
    __shared__ float red[4];

    float sc[8];
    float mx = -INFINITY;
#pragma unroll
    for (int i = 0; i < 8; ++i) {
        int s = t + i * 256;
        float x = scores[b * S_ + s];
        if (mask[b * S_ + s] == 0) x = -INFINITY;
        sc[i] = x;
        mx = fmaxf(mx, x);
    }
#pragma unroll
    for (int off = 32; off >= 1; off >>= 1) mx = fmaxf(mx, __shfl_xor(mx, off));
    if (lane == 0) red[wave] = mx;
    __syncthreads();
    mx = fmaxf(fmaxf(red[0], red[1]), fmaxf(red[2], red[3]));

    float sum = 0.f;
#pragma unroll
    for (int i = 0; i < 8; ++i) {
        float e = expf(sc[i] - mx);
        sc[i] = e;
        sum += e;
    }
#pragma unroll
    for (int off = 32; off >= 1; off >>= 1) sum += __shfl_xor(sum, off);
    __syncthreads();
    if (lane == 0) red[wave] = sum;
    __syncthreads();
    float total = red[0] + red[1] + red[2] + red[3];
    float inv = 1.f / total;
#pragma unroll
    for (int i = 0; i < 8; ++i) {
        int s = t + i * 256;
        weights[b * S_ + s] = sc[i] * inv;
    }
}

// ---------------------------------------------------------------------------
// K4a: partial context over S-segments. 2048 blocks (b, e-chunk, seg).
__global__ __launch_bounds__(256) void k_ctx_part(const float* __restrict__ X,
                                                  const float* __restrict__ weights,
                                                  float* __restrict__ part) {
    const int bid = blockIdx.x;
    const int b = bid >> 5, chunk = (bid & 31) >> 2, seg = bid & 3;
    const int t = threadIdx.x;
    __shared__ float wl[512];
    __shared__ float red[16][64];

    const int s0 = seg * 512;
    for (int i = t; i < 512; i += 256) wl[i] = weights[b * S_ + s0 + i];
    __syncthreads();

    const int lane16 = t & 15, sg = t >> 4;
    const int e0 = chunk * 64 + lane16 * 4;
    float4 acc = {0.f, 0.f, 0.f, 0.f};
#pragma unroll 4
    for (int s = sg; s < 512; s += 16) {
        float wgt = wl[s];
        float4 x = *(const float4*)&X[((size_t)b * S_ + s0 + s) * E_ + e0];
        acc.x = fmaf(wgt, x.x, acc.x);
        acc.y = fmaf(wgt, x.y, acc.y);
        acc.z = fmaf(wgt, x.z, acc.z);
        acc.w = fmaf(wgt, x.w, acc.w);
    }
    red[sg][lane16 * 4 + 0] = acc.x;
    red[sg][lane16 * 4 + 1] = acc.y;
    red[sg][lane16 * 4 + 2] = acc.z;
    red[sg][lane16 * 4 + 3] = acc.w;
    __syncthreads();
    if (t < 64) {
        float s = 0.f;
#pragma unroll
        for (int g = 0; g < 16; ++g) s += red[g][t];
        part[((size_t)b * 4 + seg) * E_ + chunk * 64 + t] = s;
    }
}

// K4b: reduce the 4 segments. 64 blocks x 512 threads.
__global__ __launch_bounds__(512) void k_ctx_final(const float* __restrict__ part,
                                                   float* __restrict__ ctx) {
    const int b = blockIdx.x, e = threadIdx.x;
    const float* p = part + (size_t)b * 4 * E_ + e;
    ctx[b * E_ + e] = p[0] + p[E_] + p[2 * E_] + p[3 * E_];
}

// ---------------------------------------------------------------------------
extern "C" void kernel_launch(void* const* d_in, const int* in_sizes, int n_in,
                              void* d_out, int out_size, void* d_ws, size_t ws_size,
                              hipStream_t stream) {
    const float* enc  = (const float*)d_in[0];
    const float* dec  = (const float*)d_in[1];
    const int*   mask = (const int*)d_in[2];
    const float* We   = (const float*)d_in[3];
    const float* Wd   = (const float*)d_in[4];
    const float* v    = (const float*)d_in[5];

    float* out     = (float*)d_out;
    float* ctx     = out;             // (B,E)
    float* weights = out + B_ * E_;   // (B,S)

    char* ws = (char*)d_ws;
    float*          ws_dec    = (float*)(ws);
    float*          ws_scores = (float*)(ws + (64 << 10));
    unsigned short* ws_bhi    = (unsigned short*)(ws + (576 << 10));
    unsigned short* ws_blo    = (unsigned short*)(ws + (832 << 10));
    float*          ws_part   = ws_scores;  // reuse after softmax consumed scores

    k_wprep<<<128, 256, 0, stream>>>(We, ws_bhi, ws_blo);
    k_decfeat<<<256, 256, 0, stream>>>(dec, Wd, ws_dec);
    k_scores<<<(B_ * S_) / 128, 256, 0, stream>>>(enc, ws_bhi, ws_blo, ws_dec, v, ws_scores);
    k_softmax<<<B_, 256, 0, stream>>>(ws_scores, mask, weights);
    k_ctx_part<<<B_ * 32, 256, 0, stream>>>(enc, weights, ws_part);
    k_ctx_final<<<B_, 512, 0, stream>>>(ws_part, ctx);
}